// Round 20
// baseline (71.495 us; speedup 1.0000x reference)
//
#include <hip/hip_runtime.h>

#define TT 1024
#define BB 32
#define KKD 8
#define NN 64
#define MM 64
#define BKC (BB*KKD)     // 256
#define KN  (KKD*NN)     // 512

typedef __attribute__((ext_vector_type(8))) _Float16 f16x8;
typedef __attribute__((ext_vector_type(2))) __fp16 fp16x2;
typedef __attribute__((ext_vector_type(4))) float f32x4;

#define SC_DOWN (1.0f/4096.0f)   // scale applied to s3 before f16 store
#define SC_UP   512.0f           // 4096 * (1/8 k-mean) applied to W

// ws layout (bytes):
//   0       : Bp   (K*N*2 f32)           = 4096
//   4096    : Wt   (64*1024 f16, row-major [m][j]) = 131072
//   135168  : state(B*K*N*6 f32)         = 393216   -> ends 528384
//   528384  : abuf — wave-interleaved layout. For (bk, t, n) with
//             q2=n>>4, nl=n&15:  uint idx =
//             (bk*4+q2)*(TL*16) + (t>>7)*2048 + (t&31)*64 + ((t>>5)&3)*16 + nl
//             (chunks for t and t+32 are ADJACENT 64B -> 128B line pair)

static __device__ __forceinline__ float bcast(float v, int lane) {
    return __builtin_bit_cast(float,
        __builtin_amdgcn_readlane(__builtin_bit_cast(int, v), lane));
}
static __device__ __forceinline__ float f16lo(unsigned int pk) {
    return (float)__builtin_bit_cast(_Float16, (unsigned short)(pk & 0xffffu));
}
static __device__ __forceinline__ float f16hi(unsigned int pk) {
    return (float)__builtin_bit_cast(_Float16, (unsigned short)(pk >> 16));
}

// ---------------- fused prep: bp (blocks 0-1) + wprep (blocks 2-257) --------
__global__ __launch_bounds__(256) void prep_kernel(const float* __restrict__ lam_re,
                                                   const float* __restrict__ lam_im,
                                                   const float* __restrict__ C_re,
                                                   const float* __restrict__ C_im,
                                                   float* __restrict__ bp,
                                                   unsigned short* __restrict__ Wt) {
    int blk = blockIdx.x;
    int tid = threadIdx.x;
    if (blk < 2) {
        int kj = blk*256 + tid;      // 0..511
        int k = kj >> 6;             // 0..7
        int j = kj & 63;
        double ljre = (double)lam_re[k*NN+j], ljim = (double)lam_im[k*NN+j];
        double inv_dj = 1.0 / (ljre*ljre + ljim*ljim);
        double pre = 1.0, pim = 0.0;
        for (int i = 0; i < NN; ++i) {
            if (i == j) continue;
            double lire = (double)lam_re[k*NN+i], liim = (double)lam_im[k*NN+i];
            double rre = (lire*ljre + liim*ljim)*inv_dj;
            double rim = (liim*ljre - lire*ljim)*inv_dj;
            double zre = 1.0 - rre, zim = -rim;      // z = 1 - lam_i/lam_j
            double npre = pre*zre - pim*zim;         // p *= z
            double npim = pre*zim + pim*zre;
            pre = npre; pim = npim;
        }
        double inv_den = 1.0 / (pre*pre + pim*pim);  // Bp = conj(p)/|p|^2
        bp[(k*NN+j)*2+0] = (float)( pre*inv_den);
        bp[(k*NN+j)*2+1] = (float)(-pim*inv_den);
    } else {
        int idx = (blk - 2)*256 + tid;   // 0..65535
        int m  = idx >> 10;
        int j  = idx & 1023;
        int kn = j >> 1;
        float v = (j & 1) ? -C_im[kn*MM + m] : C_re[kn*MM + m];
        Wt[idx] = __builtin_bit_cast(unsigned short, (_Float16)(v * SC_UP));
    }
}

// ---------------- segmented-parallel fused 3-pass scan, v6 ------------------
// v5 with pa packed to f16 pairs (papk): LDS 40960 -> 39936 B so 4 blocks/CU
// fit with slack (the exact-160KiB fit likely left only 3 resident).
// pav exchanged with the adjacent-nl lane via shfl_xor(1); even-nl lane
// stores the packed pair. Sweep reads unpack by nl parity (broadcast-free).
__global__ __launch_bounds__(512, 8) void scan_par6_kernel(const float* __restrict__ x,
                                                           const float* __restrict__ lam_re,
                                                           const float* __restrict__ lam_im,
                                                           const float* __restrict__ bp,
                                                           unsigned int* __restrict__ abuf,
                                                           int TL) {
    __shared__ float e[32][16][2];             // shared endpoint buffer (4 KB)
    __shared__ unsigned int papk[32][8];       // prefix-prod, f16x2 (1 KB)
    __shared__ unsigned int apk[32][16][17];   // [seg][step-pair][nl] (34 KB)

    int blk = blockIdx.x;       // 0..1023
    int bk = blk >> 2;
    int q2 = blk & 3;
    int b = bk >> 3;
    int k = bk & 7;
    int tid = threadIdx.x;
    int seg = tid >> 4;         // 0..31
    int nl  = tid & 15;
    int n   = q2*16 + nl;
    int kn  = k*NN + n;

    float lre = lam_re[kn], lim = lam_im[kn];
    float bpre = bp[2*kn+0], bpim = bp[2*kn+1];
    float l2 = lre*lre + lim*lim;

    float p32re = lre, p32im = lim;
    #pragma unroll
    for (int i = 0; i < 5; ++i) {
        float tr = p32re*p32re - p32im*p32im;
        float ti = 2.f*p32re*p32im;
        p32re = tr; p32im = ti;
    }

    float xs0 = x[(size_t)(seg*32 + nl)*BKC + b*KKD + k];
    float xs1 = x[(size_t)(seg*32 + 16 + nl)*BKC + b*KKD + k];

    // ---- Phase A: pass-1 local scan (zero carry) ----
    float s1re = 0.f, s1im = 0.f;
    #pragma unroll
    for (int i = 0; i < 32; ++i) {
        float xv = (i < 16) ? __shfl(xs0, i, 16) : __shfl(xs1, i - 16, 16);
        float ure = xv*bpre, uim = xv*bpim;
        float tre = __builtin_fmaf(lre, s1re, __builtin_fmaf(-lim, s1im, ure));
        float tim = __builtin_fmaf(lre, s1im, __builtin_fmaf( lim, s1re, uim));
        s1re = tre; s1im = tim;
    }
    e[seg][nl][0] = s1re; e[seg][nl][1] = s1im;
    __syncthreads();
    float c1re = 0.f, c1im = 0.f;
    for (int i = 0; i < seg; ++i) {
        float tre = __builtin_fmaf(p32re, c1re, __builtin_fmaf(-p32im, c1im, e[i][nl][0]));
        float tim = __builtin_fmaf(p32re, c1im, __builtin_fmaf( p32im, c1re, e[i][nl][1]));
        c1re = tre; c1im = tim;
    }
    __syncthreads();            // protect e before B rewrites it

    // ---- Phase B: true s1 + alpha1 (pack to LDS) + local s2 + prod(a1) ----
    s1re = c1re; s1im = c1im;
    float s2re = 0.f, s2im = 0.f, pav = 1.f;
    float a1prev = 0.f;
    #pragma unroll
    for (int i = 0; i < 32; ++i) {
        float xv = (i < 16) ? __shfl(xs0, i, 16) : __shfl(xs1, i - 16, 16);
        float ure = xv*bpre, uim = xv*bpim;
        float mm1 = __builtin_fmaf(l2, __builtin_fmaf(s1re, s1re, s1im*s1im), 1.f);
        float a1 = rsqrtf(mm1);
        float t1re = __builtin_fmaf(lre, s1re, __builtin_fmaf(-lim, s1im, ure));
        float t1im = __builtin_fmaf(lre, s1im, __builtin_fmaf( lim, s1re, uim));
        s1re = t1re; s1im = t1im;
        float cr = a1*lre, ci = a1*lim;
        float t2re = __builtin_fmaf(cr, s2re, __builtin_fmaf(-ci, s2im, ure));
        float t2im = __builtin_fmaf(cr, s2im, __builtin_fmaf( ci, s2re, uim));
        s2re = t2re; s2im = t2im;
        pav *= a1;
        if (i & 1)
            apk[seg][i>>1][nl] = __builtin_bit_cast(unsigned int,
                                   __builtin_amdgcn_cvt_pkrtz(a1prev, a1));
        else
            a1prev = a1;
    }
    e[seg][nl][0] = s2re; e[seg][nl][1] = s2im;
    {
        float pav_o = __shfl_xor(pav, 1, 64);
        if ((nl & 1) == 0)
            papk[seg][nl >> 1] = __builtin_bit_cast(unsigned int,
                                   __builtin_amdgcn_cvt_pkrtz(pav, pav_o));
    }
    __syncthreads();
    float c2re = 0.f, c2im = 0.f;
    for (int i = 0; i < seg; ++i) {
        unsigned int pp = papk[i][nl >> 1];
        float pai = (nl & 1) ? f16hi(pp) : f16lo(pp);
        float qre = pai*p32re, qim = pai*p32im;
        float tre = __builtin_fmaf(qre, c2re, __builtin_fmaf(-qim, c2im, e[i][nl][0]));
        float tim = __builtin_fmaf(qre, c2im, __builtin_fmaf( qim, c2re, e[i][nl][1]));
        c2re = tre; c2im = tim;
    }
    __syncthreads();            // protect e/papk before C rewrites them

    // ---- Phase C: pass2-true via stored a1; alpha2 -> same LDS slots ----
    s2re = c2re; s2im = c2im;
    float s3re = 0.f, s3im = 0.f, pb = 1.f;
    float a2prev = 0.f;
    unsigned int pk = 0;
    #pragma unroll
    for (int i = 0; i < 32; ++i) {
        if (!(i & 1)) pk = apk[seg][i>>1][nl];
        float a1 = (i & 1) ? f16hi(pk) : f16lo(pk);
        float xv = (i < 16) ? __shfl(xs0, i, 16) : __shfl(xs1, i - 16, 16);
        float ure = xv*bpre, uim = xv*bpim;
        float mm2 = __builtin_fmaf(l2, __builtin_fmaf(s2re, s2re, s2im*s2im), 1.f);
        float a2 = rsqrtf(mm2);
        float cr = a1*lre, ci = a1*lim;
        float t2re = __builtin_fmaf(cr, s2re, __builtin_fmaf(-ci, s2im, ure));
        float t2im = __builtin_fmaf(cr, s2im, __builtin_fmaf( ci, s2re, uim));
        s2re = t2re; s2im = t2im;
        float dr = a2*lre, di = a2*lim;
        float t3re = __builtin_fmaf(dr, s3re, __builtin_fmaf(-di, s3im, ure));
        float t3im = __builtin_fmaf(dr, s3im, __builtin_fmaf( di, s3re, uim));
        s3re = t3re; s3im = t3im;
        pb *= a2;
        if (i & 1)
            apk[seg][i>>1][nl] = __builtin_bit_cast(unsigned int,
                                   __builtin_amdgcn_cvt_pkrtz(a2prev, a2));
        else
            a2prev = a2;
    }
    e[seg][nl][0] = s3re; e[seg][nl][1] = s3im;
    {
        float pb_o = __shfl_xor(pb, 1, 64);
        if ((nl & 1) == 0)
            papk[seg][nl >> 1] = __builtin_bit_cast(unsigned int,
                                   __builtin_amdgcn_cvt_pkrtz(pb, pb_o));
    }
    __syncthreads();
    float c3re = 0.f, c3im = 0.f;
    for (int i = 0; i < seg; ++i) {
        unsigned int pp = papk[i][nl >> 1];
        float pbi = (nl & 1) ? f16hi(pp) : f16lo(pp);
        float qre = pbi*p32re, qim = pbi*p32im;
        float tre = __builtin_fmaf(qre, c3re, __builtin_fmaf(-qim, c3im, e[i][nl][0]));
        float tim = __builtin_fmaf(qre, c3im, __builtin_fmaf( qim, c3re, e[i][nl][1]));
        c3re = tre; c3im = tim;
    }

    // ---- Phase D: true s3 replay with stored alpha2; store pre-update ----
    s3re = c3re; s3im = c3im;
    unsigned int* ap = abuf + (size_t)(bk*4 + q2)*((size_t)TL*16)
                     + (seg >> 2)*2048 + (seg & 3)*16 + nl;
    #pragma unroll
    for (int i = 0; i < 32; ++i) {
        fp16x2 hv = __builtin_amdgcn_cvt_pkrtz(s3re*SC_DOWN, s3im*SC_DOWN);
        ap[(size_t)i * 64] = __builtin_bit_cast(unsigned int, hv);
        if (!(i & 1)) pk = apk[seg][i>>1][nl];
        float a2 = (i & 1) ? f16hi(pk) : f16lo(pk);
        float xv = (i < 16) ? __shfl(xs0, i, 16) : __shfl(xs1, i - 16, 16);
        float ure = xv*bpre, uim = xv*bpim;
        float dr = a2*lre, di = a2*lim;
        float t3re = __builtin_fmaf(dr, s3re, __builtin_fmaf(-di, s3im, ure));
        float t3im = __builtin_fmaf(dr, s3im, __builtin_fmaf( di, s3re, uim));
        s3re = t3re; s3im = t3im;
    }
}

// ---------------- sequential scan (chunked fallback, validated math) --------
__global__ __launch_bounds__(64) void scan_seq_kernel(const float* __restrict__ x,
                                                      const float* __restrict__ lam_re,
                                                      const float* __restrict__ lam_im,
                                                      const float* __restrict__ bp,
                                                      float* __restrict__ state,
                                                      unsigned int* __restrict__ abuf,
                                                      int chunk_start, int chunk_len,
                                                      int TL) {
    int bk = blockIdx.x;
    int b = bk >> 3;
    int k = bk & 7;
    int n = threadIdx.x;
    int kn = k*NN + n;
    float lre = lam_re[kn], lim = lam_im[kn];
    float bpre = bp[2*kn+0], bpim = bp[2*kn+1];
    float l2 = lre*lre + lim*lim;
    int chain = bk*NN + n;

    float s1re,s1im,s2re,s2im,s3re,s3im;
    if (chunk_start == 0) {
        s1re=s1im=s2re=s2im=s3re=s3im=0.f;
    } else {
        const float* st = state + (size_t)chain*6;
        s1re=st[0];s1im=st[1];s2re=st[2];s2im=st[3];s3re=st[4];s3im=st[5];
    }

    const float* xp = x + (size_t)chunk_start*BKC + b*KKD + k;
    int q2_ = n >> 4, nl_ = n & 15;
    unsigned int* ab = abuf + (size_t)(bk*4 + q2_)*((size_t)TL*16) + nl_;

    float xs = xp[(size_t)n * BKC];
    for (int t0 = 0; t0 < chunk_len; t0 += 64) {
        float xs_nxt = 0.f;
        if (t0 + 64 < chunk_len) xs_nxt = xp[(size_t)(t0 + 64 + n) * BKC];
        #pragma unroll
        for (int w = 0; w < 4; ++w) {
            float mm_[16], cre[16], cim[16];
            #pragma unroll
            for (int j = 0; j < 16; ++j) {
                float xv = bcast(xs, w*16 + j);
                mm_[j] = __builtin_fmaf(l2, s1re*s1re + s1im*s1im, 1.0f);
                float ure = xv*bpre, uim = xv*bpim;
                float tre = __builtin_fmaf(lre, s1re, __builtin_fmaf(-lim, s1im, ure));
                float tim = __builtin_fmaf(lre, s1im, __builtin_fmaf( lim, s1re, uim));
                s1re=tre; s1im=tim;
            }
            #pragma unroll
            for (int j = 0; j < 16; ++j) {
                float a = rsqrtf(mm_[j]); cre[j] = a*lre; cim[j] = a*lim;
            }
            #pragma unroll
            for (int j = 0; j < 16; ++j) {
                float xv = bcast(xs, w*16 + j);
                mm_[j] = __builtin_fmaf(l2, s2re*s2re + s2im*s2im, 1.0f);
                float ure = xv*bpre, uim = xv*bpim;
                float tre = __builtin_fmaf(cre[j], s2re, __builtin_fmaf(-cim[j], s2im, ure));
                float tim = __builtin_fmaf(cre[j], s2im, __builtin_fmaf( cim[j], s2re, uim));
                s2re=tre; s2im=tim;
            }
            #pragma unroll
            for (int j = 0; j < 16; ++j) {
                float a = rsqrtf(mm_[j]); cre[j] = a*lre; cim[j] = a*lim;
            }
            #pragma unroll
            for (int j = 0; j < 16; ++j) {
                int t = t0 + w*16 + j;
                fp16x2 hv = __builtin_amdgcn_cvt_pkrtz(s3re*SC_DOWN, s3im*SC_DOWN);
                ab[((size_t)(t >> 7))*2048 + (t & 31)*64 + ((t >> 5) & 3)*16]
                    = __builtin_bit_cast(unsigned int, hv);
                float xv = bcast(xs, w*16 + j);
                float ure = xv*bpre, uim = xv*bpim;
                float tre = __builtin_fmaf(cre[j], s3re, __builtin_fmaf(-cim[j], s3im, ure));
                float tim = __builtin_fmaf(cre[j], s3im, __builtin_fmaf( cim[j], s3re, uim));
                s3re=tre; s3im=tim;
            }
        }
        xs = xs_nxt;
    }
    float* st = state + (size_t)chain*6;
    st[0]=s1re;st[1]=s1im;st[2]=s2re;st[3]=s2im;st[4]=s3re;st[5]=s3im;
}

// MFMA f16 projection (round-16/19 validated): tile rows {t0, t0+32} x 32 b,
// 128B line pairing; double-buffered LDS (At + Wb); ISSUE -> COMPUTE ->
// WRITE -> barrier; XOR swizzle u^(row&7).
__global__ __launch_bounds__(256) void proj_kernel(const unsigned int* __restrict__ A,
                                                   const unsigned short* __restrict__ Wt,
                                                   const float* __restrict__ x,
                                                   const float* __restrict__ D,
                                                   const float* __restrict__ Do,
                                                   float* __restrict__ out,
                                                   int rowOff, int TL) {
    __shared__ uint4 At[2][1024];        // [buf][row*16 + u^(row&7)]  16 KB each
    __shared__ uint4 Wb[2][1024];
    int tid = threadIdx.x;
    int w = tid >> 6, l = tid & 63;
    int lg = l >> 4, lr = l & 15;
    int wr = w >> 1, wc = w & 1;
    int bI = blockIdx.x;
    int t0 = ((bI >> 5) << 6) + (bI & 31);   // local t base; pairs with t0+32
    size_t TLQ = (size_t)TL * 16;            // uints per (bk,q2) region

    f32x4 acc[2][2];
    #pragma unroll
    for (int g = 0; g < 2; ++g)
        #pragma unroll
        for (int t = 0; t < 2; ++t) acc[g][t] = (f32x4){0.f,0.f,0.f,0.f};

    uint4 ra[4], rw[4];
    int srow[4], su[4];
    #pragma unroll
    for (int i = 0; i < 4; ++i) {
        int unit = w*256 + i*64 + l;
        srow[i] = unit >> 4;
        su[i]   = unit & 15;
    }

    // ---- ISSUE + WRITE chunk 0 ----
    #pragma unroll
    for (int i = 0; i < 4; ++i) {
        int row = srow[i], u = su[i];
        int b = row & 31, t2 = t0 + ((row >> 5) << 5);
        size_t idx = (size_t)((b*8 + 0)*4 + (u >> 2))*TLQ
                   + (size_t)(t2 >> 7)*2048 + (t2 & 31)*64 + ((t2 >> 5) & 3)*16 + (u & 3)*4;
        ra[i] = *(const uint4*)(A + idx);
        rw[i] = *(const uint4*)((const char*)Wt + (row*2048 + 0*256 + u*16));
    }
    #pragma unroll
    for (int i = 0; i < 4; ++i) {
        int row = srow[i], u = su[i];
        At[0][row*16 + (u ^ (row & 7))] = ra[i];
        Wb[0][row*16 + (u ^ (row & 7))] = rw[i];
    }
    __syncthreads();

    for (int kc = 0; kc < 8; ++kc) {
        int cur = kc & 1;
        if (kc < 7) {
            int kn = kc + 1;
            #pragma unroll
            for (int i = 0; i < 4; ++i) {
                int row = srow[i], u = su[i];
                int b = row & 31, t2 = t0 + ((row >> 5) << 5);
                size_t idx = (size_t)((b*8 + kn)*4 + (u >> 2))*TLQ
                           + (size_t)(t2 >> 7)*2048 + (t2 & 31)*64 + ((t2 >> 5) & 3)*16 + (u & 3)*4;
                ra[i] = *(const uint4*)(A + idx);
                rw[i] = *(const uint4*)((const char*)Wt + (row*2048 + kn*256 + u*16));
            }
        }
        #pragma unroll
        for (int ks = 0; ks < 4; ++ks) {
            f16x8 af[2], bf[2];
            #pragma unroll
            for (int g = 0; g < 2; ++g) {
                int row = (wr*2 + g)*16 + lr;
                af[g] = __builtin_bit_cast(f16x8, At[cur][row*16 + ((ks*4 + lg) ^ (row & 7))]);
            }
            #pragma unroll
            for (int t = 0; t < 2; ++t) {
                int m = (wc*2 + t)*16 + lr;
                bf[t] = __builtin_bit_cast(f16x8, Wb[cur][m*16 + ((ks*4 + lg) ^ (m & 7))]);
            }
            #pragma unroll
            for (int g = 0; g < 2; ++g)
                #pragma unroll
                for (int t = 0; t < 2; ++t)
                    acc[g][t] = __builtin_amdgcn_mfma_f32_16x16x32_f16(af[g], bf[t], acc[g][t], 0,0,0);
        }
        if (kc < 7) {
            int nb = (kc + 1) & 1;
            #pragma unroll
            for (int i = 0; i < 4; ++i) {
                int row = srow[i], u = su[i];
                At[nb][row*16 + (u ^ (row & 7))] = ra[i];
                Wb[nb][row*16 + (u ^ (row & 7))] = rw[i];
            }
        }
        __syncthreads();
    }

    // ---- epilogue: appended K=32 mfma for (x·D + sum_k Do)/8 ----
    #pragma unroll
    for (int g = 0; g < 2; ++g) {
        int row_o = (wr*2 + g)*16 + lr;
        int grow = rowOff + (t0 + ((row_o >> 5) << 5))*32 + (row_o & 31);
        const float* xr = x + (size_t)grow * KKD;
        float4 x0 = *(const float4*)(xr);
        float4 x1 = *(const float4*)(xr + 4);
        f16x8 a2;
        a2[0] = (lg==0) ? (_Float16)x0.x : ((lg==1) ? (_Float16)1.0f : (_Float16)0.0f);
        a2[1] = (lg==0) ? (_Float16)x0.y : (_Float16)0.0f;
        a2[2] = (lg==0) ? (_Float16)x0.z : (_Float16)0.0f;
        a2[3] = (lg==0) ? (_Float16)x0.w : (_Float16)0.0f;
        a2[4] = (lg==0) ? (_Float16)x1.x : (_Float16)0.0f;
        a2[5] = (lg==0) ? (_Float16)x1.y : (_Float16)0.0f;
        a2[6] = (lg==0) ? (_Float16)x1.z : (_Float16)0.0f;
        a2[7] = (lg==0) ? (_Float16)x1.w : (_Float16)0.0f;
        #pragma unroll
        for (int t = 0; t < 2; ++t) {
            int c = (wc*2 + t)*16 + lr;
            float dob = 0.f;
            #pragma unroll
            for (int i = 0; i < 8; ++i) dob += Do[i*64 + c];
            f16x8 b2;
            b2[0] = (lg==0) ? (_Float16)(D[0*64+c]*0.125f)
                  : ((lg==1) ? (_Float16)(dob*0.125f) : (_Float16)0.0f);
            b2[1] = (lg==0) ? (_Float16)(D[1*64+c]*0.125f) : (_Float16)0.0f;
            b2[2] = (lg==0) ? (_Float16)(D[2*64+c]*0.125f) : (_Float16)0.0f;
            b2[3] = (lg==0) ? (_Float16)(D[3*64+c]*0.125f) : (_Float16)0.0f;
            b2[4] = (lg==0) ? (_Float16)(D[4*64+c]*0.125f) : (_Float16)0.0f;
            b2[5] = (lg==0) ? (_Float16)(D[5*64+c]*0.125f) : (_Float16)0.0f;
            b2[6] = (lg==0) ? (_Float16)(D[6*64+c]*0.125f) : (_Float16)0.0f;
            b2[7] = (lg==0) ? (_Float16)(D[7*64+c]*0.125f) : (_Float16)0.0f;
            acc[g][t] = __builtin_amdgcn_mfma_f32_16x16x32_f16(a2, b2, acc[g][t], 0,0,0);
        }
    }

    #pragma unroll
    for (int g = 0; g < 2; ++g)
        #pragma unroll
        for (int t = 0; t < 2; ++t) {
            int c = (wc*2 + t)*16 + lr;
            #pragma unroll
            for (int reg = 0; reg < 4; ++reg) {
                int row_o = (wr*2 + g)*16 + lg*4 + reg;
                int grow = rowOff + (t0 + ((row_o >> 5) << 5))*32 + (row_o & 31);
                out[(size_t)grow*MM + c] = acc[g][t][reg];
            }
        }
}

extern "C" void kernel_launch(void* const* d_in, const int* in_sizes, int n_in,
                              void* d_out, int out_size, void* d_ws, size_t ws_size,
                              hipStream_t stream) {
    const float* x      = (const float*)d_in[0];
    const float* lam_re = (const float*)d_in[1];
    const float* lam_im = (const float*)d_in[2];
    const float* C_re   = (const float*)d_in[3];
    const float* C_im   = (const float*)d_in[4];
    const float* D      = (const float*)d_in[5];
    const float* Do     = (const float*)d_in[6];
    float* out = (float*)d_out;

    char* ws = (char*)d_ws;
    float*          bpw    = (float*)(ws);
    unsigned short* Wt     = (unsigned short*)(ws + 4096);
    float*          statew = (float*)(ws + 135168);
    unsigned int*   abuf   = (unsigned int*)(ws + 528384);

    prep_kernel<<<258, 256, 0, stream>>>(lam_re, lam_im, C_re, C_im, bpw, Wt);

    const size_t base = 528384;
    const size_t perT = (size_t)BB*KN*4;     // 65536 B per timestep

    if (ws_size >= base + (size_t)TT*perT) {
        // full-T path: quarter-split segmented-parallel scan (4 blocks/CU)
        scan_par6_kernel<<<BKC*4, 512, 0, stream>>>(x, lam_re, lam_im, bpw, abuf, TT);
        proj_kernel<<<TT*BB/64, 256, 0, stream>>>(abuf, Wt, x, D, Do, out, 0, TT);
    } else {
        // chunked fallback
        size_t avail = ws_size > base ? ws_size - base : 0;
        int chunkT = (int)(avail / perT) & ~127;
        if (chunkT < 128) chunkT = 128;
        for (int cs = 0; cs < TT; cs += chunkT) {
            int len = (chunkT < TT - cs) ? chunkT : (TT - cs);
            scan_seq_kernel<<<BKC, NN, 0, stream>>>(x, lam_re, lam_im, bpw, statew,
                                                    abuf, cs, len, len);
            proj_kernel<<<len*BB/64, 256, 0, stream>>>(abuf, Wt, x, D, Do, out,
                                                       cs*BB, len);
        }
    }
}

// Round 21
// 68.693 us; speedup vs baseline: 1.0408x; 1.0408x over previous
//
#include <hip/hip_runtime.h>

#define TT 1024
#define BB 32
#define KKD 8
#define NN 64
#define MM 64
#define BKC (BB*KKD)     // 256
#define KN  (KKD*NN)     // 512

typedef __attribute__((ext_vector_type(8))) _Float16 f16x8;
typedef __attribute__((ext_vector_type(2))) __fp16 fp16x2;
typedef __attribute__((ext_vector_type(4))) float f32x4;

#define SC_DOWN (1.0f/4096.0f)   // scale applied to s3 before f16 store
#define SC_UP   512.0f           // 4096 * (1/8 k-mean) applied to W

// ws layout (bytes):
//   0       : Bp   (K*N*2 f32)           = 4096
//   4096    : Wt   (64*1024 f16, row-major [m][j]) = 131072
//   135168  : state(B*K*N*6 f32)         = 393216   -> ends 528384
//   528384  : abuf — wave-interleaved layout. For (bk, t, n) with
//             q2=n>>4, nl=n&15:  uint idx =
//             (bk*4+q2)*(TL*16) + (t>>7)*2048 + (t&31)*64 + ((t>>5)&3)*16 + nl
//             (chunks for t and t+32 are ADJACENT 64B -> 128B line pair)

static __device__ __forceinline__ float bcast(float v, int lane) {
    return __builtin_bit_cast(float,
        __builtin_amdgcn_readlane(__builtin_bit_cast(int, v), lane));
}
static __device__ __forceinline__ float f16lo(unsigned int pk) {
    return (float)__builtin_bit_cast(_Float16, (unsigned short)(pk & 0xffffu));
}
static __device__ __forceinline__ float f16hi(unsigned int pk) {
    return (float)__builtin_bit_cast(_Float16, (unsigned short)(pk >> 16));
}

// ---------------- fused prep: bp (blocks 0-1) + wprep (blocks 2-257) --------
// bp: division-free — p = prod(z_i), Bp = 1/p = conj(p)/|p|^2.
__global__ __launch_bounds__(256) void prep_kernel(const float* __restrict__ lam_re,
                                                   const float* __restrict__ lam_im,
                                                   const float* __restrict__ C_re,
                                                   const float* __restrict__ C_im,
                                                   float* __restrict__ bp,
                                                   unsigned short* __restrict__ Wt) {
    int blk = blockIdx.x;
    int tid = threadIdx.x;
    if (blk < 2) {
        int kj = blk*256 + tid;      // 0..511
        int k = kj >> 6;             // 0..7
        int j = kj & 63;
        double ljre = (double)lam_re[k*NN+j], ljim = (double)lam_im[k*NN+j];
        double inv_dj = 1.0 / (ljre*ljre + ljim*ljim);
        double pre = 1.0, pim = 0.0;
        for (int i = 0; i < NN; ++i) {
            if (i == j) continue;
            double lire = (double)lam_re[k*NN+i], liim = (double)lam_im[k*NN+i];
            double rre = (lire*ljre + liim*ljim)*inv_dj;
            double rim = (liim*ljre - lire*ljim)*inv_dj;
            double zre = 1.0 - rre, zim = -rim;      // z = 1 - lam_i/lam_j
            double npre = pre*zre - pim*zim;         // p *= z
            double npim = pre*zim + pim*zre;
            pre = npre; pim = npim;
        }
        double inv_den = 1.0 / (pre*pre + pim*pim);  // Bp = conj(p)/|p|^2
        bp[(k*NN+j)*2+0] = (float)( pre*inv_den);
        bp[(k*NN+j)*2+1] = (float)(-pim*inv_den);
    } else {
        int idx = (blk - 2)*256 + tid;   // 0..65535
        int m  = idx >> 10;
        int j  = idx & 1023;
        int kn = j >> 1;
        float v = (j & 1) ? -C_im[kn*MM + m] : C_re[kn*MM + m];
        Wt[idx] = __builtin_bit_cast(unsigned short, (_Float16)(v * SC_UP));
    }
}

// ---------------- segmented-parallel fused 3-pass scan, v5 ------------------
__global__ __launch_bounds__(512, 8) void scan_par5_kernel(const float* __restrict__ x,
                                                           const float* __restrict__ lam_re,
                                                           const float* __restrict__ lam_im,
                                                           const float* __restrict__ bp,
                                                           unsigned int* __restrict__ abuf,
                                                           int TL) {
    __shared__ float e[32][16][2];             // shared endpoint buffer (4 KB)
    __shared__ float pa[32][16];               // shared prefix-prod (2 KB)
    __shared__ unsigned int apk[32][16][17];   // [seg][step-pair][nl] (34 KB)

    int blk = blockIdx.x;       // 0..1023
    int bk = blk >> 2;
    int q2 = blk & 3;
    int b = bk >> 3;
    int k = bk & 7;
    int tid = threadIdx.x;
    int seg = tid >> 4;         // 0..31
    int nl  = tid & 15;
    int n   = q2*16 + nl;
    int kn  = k*NN + n;

    float lre = lam_re[kn], lim = lam_im[kn];
    float bpre = bp[2*kn+0], bpim = bp[2*kn+1];
    float l2 = lre*lre + lim*lim;

    float p32re = lre, p32im = lim;
    #pragma unroll
    for (int i = 0; i < 5; ++i) {
        float tr = p32re*p32re - p32im*p32im;
        float ti = 2.f*p32re*p32im;
        p32re = tr; p32im = ti;
    }

    float xs0 = x[(size_t)(seg*32 + nl)*BKC + b*KKD + k];
    float xs1 = x[(size_t)(seg*32 + 16 + nl)*BKC + b*KKD + k];

    // ---- Phase A ----
    float s1re = 0.f, s1im = 0.f;
    #pragma unroll
    for (int i = 0; i < 32; ++i) {
        float xv = (i < 16) ? __shfl(xs0, i, 16) : __shfl(xs1, i - 16, 16);
        float ure = xv*bpre, uim = xv*bpim;
        float tre = __builtin_fmaf(lre, s1re, __builtin_fmaf(-lim, s1im, ure));
        float tim = __builtin_fmaf(lre, s1im, __builtin_fmaf( lim, s1re, uim));
        s1re = tre; s1im = tim;
    }
    e[seg][nl][0] = s1re; e[seg][nl][1] = s1im;
    __syncthreads();
    float c1re = 0.f, c1im = 0.f;
    for (int i = 0; i < seg; ++i) {
        float tre = __builtin_fmaf(p32re, c1re, __builtin_fmaf(-p32im, c1im, e[i][nl][0]));
        float tim = __builtin_fmaf(p32re, c1im, __builtin_fmaf( p32im, c1re, e[i][nl][1]));
        c1re = tre; c1im = tim;
    }
    __syncthreads();            // protect e before B rewrites it

    // ---- Phase B ----
    s1re = c1re; s1im = c1im;
    float s2re = 0.f, s2im = 0.f, pav = 1.f;
    float a1prev = 0.f;
    #pragma unroll
    for (int i = 0; i < 32; ++i) {
        float xv = (i < 16) ? __shfl(xs0, i, 16) : __shfl(xs1, i - 16, 16);
        float ure = xv*bpre, uim = xv*bpim;
        float mm1 = __builtin_fmaf(l2, __builtin_fmaf(s1re, s1re, s1im*s1im), 1.f);
        float a1 = rsqrtf(mm1);
        float t1re = __builtin_fmaf(lre, s1re, __builtin_fmaf(-lim, s1im, ure));
        float t1im = __builtin_fmaf(lre, s1im, __builtin_fmaf( lim, s1re, uim));
        s1re = t1re; s1im = t1im;
        float cr = a1*lre, ci = a1*lim;
        float t2re = __builtin_fmaf(cr, s2re, __builtin_fmaf(-ci, s2im, ure));
        float t2im = __builtin_fmaf(cr, s2im, __builtin_fmaf( ci, s2re, uim));
        s2re = t2re; s2im = t2im;
        pav *= a1;
        if (i & 1)
            apk[seg][i>>1][nl] = __builtin_bit_cast(unsigned int,
                                   __builtin_amdgcn_cvt_pkrtz(a1prev, a1));
        else
            a1prev = a1;
    }
    e[seg][nl][0] = s2re; e[seg][nl][1] = s2im; pa[seg][nl] = pav;
    __syncthreads();
    float c2re = 0.f, c2im = 0.f;
    for (int i = 0; i < seg; ++i) {
        float pai = pa[i][nl];
        float qre = pai*p32re, qim = pai*p32im;
        float tre = __builtin_fmaf(qre, c2re, __builtin_fmaf(-qim, c2im, e[i][nl][0]));
        float tim = __builtin_fmaf(qre, c2im, __builtin_fmaf( qim, c2re, e[i][nl][1]));
        c2re = tre; c2im = tim;
    }
    __syncthreads();            // protect e/pa before C rewrites them

    // ---- Phase C ----
    s2re = c2re; s2im = c2im;
    float s3re = 0.f, s3im = 0.f, pb = 1.f;
    float a2prev = 0.f;
    unsigned int pk = 0;
    #pragma unroll
    for (int i = 0; i < 32; ++i) {
        if (!(i & 1)) pk = apk[seg][i>>1][nl];
        float a1 = (i & 1) ? f16hi(pk) : f16lo(pk);
        float xv = (i < 16) ? __shfl(xs0, i, 16) : __shfl(xs1, i - 16, 16);
        float ure = xv*bpre, uim = xv*bpim;
        float mm2 = __builtin_fmaf(l2, __builtin_fmaf(s2re, s2re, s2im*s2im), 1.f);
        float a2 = rsqrtf(mm2);
        float cr = a1*lre, ci = a1*lim;
        float t2re = __builtin_fmaf(cr, s2re, __builtin_fmaf(-ci, s2im, ure));
        float t2im = __builtin_fmaf(cr, s2im, __builtin_fmaf( ci, s2re, uim));
        s2re = t2re; s2im = t2im;
        float dr = a2*lre, di = a2*lim;
        float t3re = __builtin_fmaf(dr, s3re, __builtin_fmaf(-di, s3im, ure));
        float t3im = __builtin_fmaf(dr, s3im, __builtin_fmaf( di, s3re, uim));
        s3re = t3re; s3im = t3im;
        pb *= a2;
        if (i & 1)
            apk[seg][i>>1][nl] = __builtin_bit_cast(unsigned int,
                                   __builtin_amdgcn_cvt_pkrtz(a2prev, a2));
        else
            a2prev = a2;
    }
    e[seg][nl][0] = s3re; e[seg][nl][1] = s3im; pa[seg][nl] = pb;
    __syncthreads();
    float c3re = 0.f, c3im = 0.f;
    for (int i = 0; i < seg; ++i) {
        float pbi = pa[i][nl];
        float qre = pbi*p32re, qim = pbi*p32im;
        float tre = __builtin_fmaf(qre, c3re, __builtin_fmaf(-qim, c3im, e[i][nl][0]));
        float tim = __builtin_fmaf(qre, c3im, __builtin_fmaf( qim, c3re, e[i][nl][1]));
        c3re = tre; c3im = tim;
    }

    // ---- Phase D ----
    s3re = c3re; s3im = c3im;
    unsigned int* ap = abuf + (size_t)(bk*4 + q2)*((size_t)TL*16)
                     + (seg >> 2)*2048 + (seg & 3)*16 + nl;
    #pragma unroll
    for (int i = 0; i < 32; ++i) {
        fp16x2 hv = __builtin_amdgcn_cvt_pkrtz(s3re*SC_DOWN, s3im*SC_DOWN);
        ap[(size_t)i * 64] = __builtin_bit_cast(unsigned int, hv);
        if (!(i & 1)) pk = apk[seg][i>>1][nl];
        float a2 = (i & 1) ? f16hi(pk) : f16lo(pk);
        float xv = (i < 16) ? __shfl(xs0, i, 16) : __shfl(xs1, i - 16, 16);
        float ure = xv*bpre, uim = xv*bpim;
        float dr = a2*lre, di = a2*lim;
        float t3re = __builtin_fmaf(dr, s3re, __builtin_fmaf(-di, s3im, ure));
        float t3im = __builtin_fmaf(dr, s3im, __builtin_fmaf( di, s3re, uim));
        s3re = t3re; s3im = t3im;
    }
}

// ---------------- sequential scan (chunked fallback, validated math) --------
__global__ __launch_bounds__(64) void scan_seq_kernel(const float* __restrict__ x,
                                                      const float* __restrict__ lam_re,
                                                      const float* __restrict__ lam_im,
                                                      const float* __restrict__ bp,
                                                      float* __restrict__ state,
                                                      unsigned int* __restrict__ abuf,
                                                      int chunk_start, int chunk_len,
                                                      int TL) {
    int bk = blockIdx.x;
    int b = bk >> 3;
    int k = bk & 7;
    int n = threadIdx.x;
    int kn = k*NN + n;
    float lre = lam_re[kn], lim = lam_im[kn];
    float bpre = bp[2*kn+0], bpim = bp[2*kn+1];
    float l2 = lre*lre + lim*lim;
    int chain = bk*NN + n;

    float s1re,s1im,s2re,s2im,s3re,s3im;
    if (chunk_start == 0) {
        s1re=s1im=s2re=s2im=s3re=s3im=0.f;
    } else {
        const float* st = state + (size_t)chain*6;
        s1re=st[0];s1im=st[1];s2re=st[2];s2im=st[3];s3re=st[4];s3im=st[5];
    }

    const float* xp = x + (size_t)chunk_start*BKC + b*KKD + k;
    int q2_ = n >> 4, nl_ = n & 15;
    unsigned int* ab = abuf + (size_t)(bk*4 + q2_)*((size_t)TL*16) + nl_;

    float xs = xp[(size_t)n * BKC];
    for (int t0 = 0; t0 < chunk_len; t0 += 64) {
        float xs_nxt = 0.f;
        if (t0 + 64 < chunk_len) xs_nxt = xp[(size_t)(t0 + 64 + n) * BKC];
        #pragma unroll
        for (int w = 0; w < 4; ++w) {
            float mm_[16], cre[16], cim[16];
            #pragma unroll
            for (int j = 0; j < 16; ++j) {
                float xv = bcast(xs, w*16 + j);
                mm_[j] = __builtin_fmaf(l2, s1re*s1re + s1im*s1im, 1.0f);
                float ure = xv*bpre, uim = xv*bpim;
                float tre = __builtin_fmaf(lre, s1re, __builtin_fmaf(-lim, s1im, ure));
                float tim = __builtin_fmaf(lre, s1im, __builtin_fmaf( lim, s1re, uim));
                s1re=tre; s1im=tim;
            }
            #pragma unroll
            for (int j = 0; j < 16; ++j) {
                float a = rsqrtf(mm_[j]); cre[j] = a*lre; cim[j] = a*lim;
            }
            #pragma unroll
            for (int j = 0; j < 16; ++j) {
                float xv = bcast(xs, w*16 + j);
                mm_[j] = __builtin_fmaf(l2, s2re*s2re + s2im*s2im, 1.0f);
                float ure = xv*bpre, uim = xv*bpim;
                float tre = __builtin_fmaf(cre[j], s2re, __builtin_fmaf(-cim[j], s2im, ure));
                float tim = __builtin_fmaf(cre[j], s2im, __builtin_fmaf( cim[j], s2re, uim));
                s2re=tre; s2im=tim;
            }
            #pragma unroll
            for (int j = 0; j < 16; ++j) {
                float a = rsqrtf(mm_[j]); cre[j] = a*lre; cim[j] = a*lim;
            }
            #pragma unroll
            for (int j = 0; j < 16; ++j) {
                int t = t0 + w*16 + j;
                fp16x2 hv = __builtin_amdgcn_cvt_pkrtz(s3re*SC_DOWN, s3im*SC_DOWN);
                ab[((size_t)(t >> 7))*2048 + (t & 31)*64 + ((t >> 5) & 3)*16]
                    = __builtin_bit_cast(unsigned int, hv);
                float xv = bcast(xs, w*16 + j);
                float ure = xv*bpre, uim = xv*bpim;
                float tre = __builtin_fmaf(cre[j], s3re, __builtin_fmaf(-cim[j], s3im, ure));
                float tim = __builtin_fmaf(cre[j], s3im, __builtin_fmaf( cim[j], s3re, uim));
                s3re=tre; s3im=tim;
            }
        }
        xs = xs_nxt;
    }
    float* st = state + (size_t)chain*6;
    st[0]=s1re;st[1]=s1im;st[2]=s2re;st[3]=s2im;st[4]=s3re;st[5]=s3im;
}

// MFMA f16 projection (validated): tile rows {t0, t0+32} x 32 b pairs
// adjacent 64B chunks into full 128B lines. Double-buffered LDS (At + Wb);
// ISSUE(c+1) -> COMPUTE(c) -> WRITE(c+1) -> barrier; XOR swizzle u^(row&7).
__global__ __launch_bounds__(256) void proj_kernel(const unsigned int* __restrict__ A,
                                                   const unsigned short* __restrict__ Wt,
                                                   const float* __restrict__ x,
                                                   const float* __restrict__ D,
                                                   const float* __restrict__ Do,
                                                   float* __restrict__ out,
                                                   int rowOff, int TL) {
    __shared__ uint4 At[2][1024];        // [buf][row*16 + u^(row&7)]  16 KB each
    __shared__ uint4 Wb[2][1024];
    int tid = threadIdx.x;
    int w = tid >> 6, l = tid & 63;
    int lg = l >> 4, lr = l & 15;
    int wr = w >> 1, wc = w & 1;
    int bI = blockIdx.x;
    int t0 = ((bI >> 5) << 6) + (bI & 31);   // local t base; pairs with t0+32
    size_t TLQ = (size_t)TL * 16;            // uints per (bk,q2) region

    f32x4 acc[2][2];
    #pragma unroll
    for (int g = 0; g < 2; ++g)
        #pragma unroll
        for (int t = 0; t < 2; ++t) acc[g][t] = (f32x4){0.f,0.f,0.f,0.f};

    uint4 ra[4], rw[4];
    int srow[4], su[4];
    #pragma unroll
    for (int i = 0; i < 4; ++i) {
        int unit = w*256 + i*64 + l;
        srow[i] = unit >> 4;
        su[i]   = unit & 15;
    }

    // ---- ISSUE + WRITE chunk 0 ----
    #pragma unroll
    for (int i = 0; i < 4; ++i) {
        int row = srow[i], u = su[i];
        int b = row & 31, t2 = t0 + ((row >> 5) << 5);
        size_t idx = (size_t)((b*8 + 0)*4 + (u >> 2))*TLQ
                   + (size_t)(t2 >> 7)*2048 + (t2 & 31)*64 + ((t2 >> 5) & 3)*16 + (u & 3)*4;
        ra[i] = *(const uint4*)(A + idx);
        rw[i] = *(const uint4*)((const char*)Wt + (row*2048 + 0*256 + u*16));
    }
    #pragma unroll
    for (int i = 0; i < 4; ++i) {
        int row = srow[i], u = su[i];
        At[0][row*16 + (u ^ (row & 7))] = ra[i];
        Wb[0][row*16 + (u ^ (row & 7))] = rw[i];
    }
    __syncthreads();

    for (int kc = 0; kc < 8; ++kc) {
        int cur = kc & 1;
        if (kc < 7) {
            int kn = kc + 1;
            #pragma unroll
            for (int i = 0; i < 4; ++i) {
                int row = srow[i], u = su[i];
                int b = row & 31, t2 = t0 + ((row >> 5) << 5);
                size_t idx = (size_t)((b*8 + kn)*4 + (u >> 2))*TLQ
                           + (size_t)(t2 >> 7)*2048 + (t2 & 31)*64 + ((t2 >> 5) & 3)*16 + (u & 3)*4;
                ra[i] = *(const uint4*)(A + idx);
                rw[i] = *(const uint4*)((const char*)Wt + (row*2048 + kn*256 + u*16));
            }
        }
        #pragma unroll
        for (int ks = 0; ks < 4; ++ks) {
            f16x8 af[2], bf[2];
            #pragma unroll
            for (int g = 0; g < 2; ++g) {
                int row = (wr*2 + g)*16 + lr;
                af[g] = __builtin_bit_cast(f16x8, At[cur][row*16 + ((ks*4 + lg) ^ (row & 7))]);
            }
            #pragma unroll
            for (int t = 0; t < 2; ++t) {
                int m = (wc*2 + t)*16 + lr;
                bf[t] = __builtin_bit_cast(f16x8, Wb[cur][m*16 + ((ks*4 + lg) ^ (m & 7))]);
            }
            #pragma unroll
            for (int g = 0; g < 2; ++g)
                #pragma unroll
                for (int t = 0; t < 2; ++t)
                    acc[g][t] = __builtin_amdgcn_mfma_f32_16x16x32_f16(af[g], bf[t], acc[g][t], 0,0,0);
        }
        if (kc < 7) {
            int nb = (kc + 1) & 1;
            #pragma unroll
            for (int i = 0; i < 4; ++i) {
                int row = srow[i], u = su[i];
                At[nb][row*16 + (u ^ (row & 7))] = ra[i];
                Wb[nb][row*16 + (u ^ (row & 7))] = rw[i];
            }
        }
        __syncthreads();
    }

    // ---- epilogue: appended K=32 mfma for (x·D + sum_k Do)/8 ----
    #pragma unroll
    for (int g = 0; g < 2; ++g) {
        int row_o = (wr*2 + g)*16 + lr;
        int grow = rowOff + (t0 + ((row_o >> 5) << 5))*32 + (row_o & 31);
        const float* xr = x + (size_t)grow * KKD;
        float4 x0 = *(const float4*)(xr);
        float4 x1 = *(const float4*)(xr + 4);
        f16x8 a2;
        a2[0] = (lg==0) ? (_Float16)x0.x : ((lg==1) ? (_Float16)1.0f : (_Float16)0.0f);
        a2[1] = (lg==0) ? (_Float16)x0.y : (_Float16)0.0f;
        a2[2] = (lg==0) ? (_Float16)x0.z : (_Float16)0.0f;
        a2[3] = (lg==0) ? (_Float16)x0.w : (_Float16)0.0f;
        a2[4] = (lg==0) ? (_Float16)x1.x : (_Float16)0.0f;
        a2[5] = (lg==0) ? (_Float16)x1.y : (_Float16)0.0f;
        a2[6] = (lg==0) ? (_Float16)x1.z : (_Float16)0.0f;
        a2[7] = (lg==0) ? (_Float16)x1.w : (_Float16)0.0f;
        #pragma unroll
        for (int t = 0; t < 2; ++t) {
            int c = (wc*2 + t)*16 + lr;
            float dob = 0.f;
            #pragma unroll
            for (int i = 0; i < 8; ++i) dob += Do[i*64 + c];
            f16x8 b2;
            b2[0] = (lg==0) ? (_Float16)(D[0*64+c]*0.125f)
                  : ((lg==1) ? (_Float16)(dob*0.125f) : (_Float16)0.0f);
            b2[1] = (lg==0) ? (_Float16)(D[1*64+c]*0.125f) : (_Float16)0.0f;
            b2[2] = (lg==0) ? (_Float16)(D[2*64+c]*0.125f) : (_Float16)0.0f;
            b2[3] = (lg==0) ? (_Float16)(D[3*64+c]*0.125f) : (_Float16)0.0f;
            b2[4] = (lg==0) ? (_Float16)(D[4*64+c]*0.125f) : (_Float16)0.0f;
            b2[5] = (lg==0) ? (_Float16)(D[5*64+c]*0.125f) : (_Float16)0.0f;
            b2[6] = (lg==0) ? (_Float16)(D[6*64+c]*0.125f) : (_Float16)0.0f;
            b2[7] = (lg==0) ? (_Float16)(D[7*64+c]*0.125f) : (_Float16)0.0f;
            acc[g][t] = __builtin_amdgcn_mfma_f32_16x16x32_f16(a2, b2, acc[g][t], 0,0,0);
        }
    }

    #pragma unroll
    for (int g = 0; g < 2; ++g)
        #pragma unroll
        for (int t = 0; t < 2; ++t) {
            int c = (wc*2 + t)*16 + lr;
            #pragma unroll
            for (int reg = 0; reg < 4; ++reg) {
                int row_o = (wr*2 + g)*16 + lg*4 + reg;
                int grow = rowOff + (t0 + ((row_o >> 5) << 5))*32 + (row_o & 31);
                out[(size_t)grow*MM + c] = acc[g][t][reg];
            }
        }
}

extern "C" void kernel_launch(void* const* d_in, const int* in_sizes, int n_in,
                              void* d_out, int out_size, void* d_ws, size_t ws_size,
                              hipStream_t stream) {
    const float* x      = (const float*)d_in[0];
    const float* lam_re = (const float*)d_in[1];
    const float* lam_im = (const float*)d_in[2];
    const float* C_re   = (const float*)d_in[3];
    const float* C_im   = (const float*)d_in[4];
    const float* D      = (const float*)d_in[5];
    const float* Do     = (const float*)d_in[6];
    float* out = (float*)d_out;

    char* ws = (char*)d_ws;
    float*          bpw    = (float*)(ws);
    unsigned short* Wt     = (unsigned short*)(ws + 4096);
    float*          statew = (float*)(ws + 135168);
    unsigned int*   abuf   = (unsigned int*)(ws + 528384);

    prep_kernel<<<258, 256, 0, stream>>>(lam_re, lam_im, C_re, C_im, bpw, Wt);

    const size_t base = 528384;
    const size_t perT = (size_t)BB*KN*4;     // 65536 B per timestep

    if (ws_size >= base + (size_t)TT*perT) {
        // full-T path: quarter-split segmented-parallel scan (4 blocks/CU)
        scan_par5_kernel<<<BKC*4, 512, 0, stream>>>(x, lam_re, lam_im, bpw, abuf, TT);
        proj_kernel<<<TT*BB/64, 256, 0, stream>>>(abuf, Wt, x, D, Do, out, 0, TT);
    } else {
        // chunked fallback
        size_t avail = ws_size > base ? ws_size - base : 0;
        int chunkT = (int)(avail / perT) & ~127;
        if (chunkT < 128) chunkT = 128;
        for (int cs = 0; cs < TT; cs += chunkT) {
            int len = (chunkT < TT - cs) ? chunkT : (TT - cs);
            scan_seq_kernel<<<BKC, NN, 0, stream>>>(x, lam_re, lam_im, bpw, statew,
                                                    abuf, cs, len, len);
            proj_kernel<<<len*BB/64, 256, 0, stream>>>(abuf, Wt, x, D, Do, out,
                                                       cs*BB, len);
        }
    }
}